// Round 11
// baseline (184.706 us; speedup 1.0000x reference)
//
#include <hip/hip_runtime.h>

#define N_TOT 8192
#define SEQ_L 512
#define D 128
#define NCHUNK 16
#define CHUNK (N_TOT / NCHUNK)   // 512 cols per j-chunk == one seq block
#define LOG2E 1.4426950408889634f
#define LN2   0.6931471805599453f

using bf16x8  = __attribute__((ext_vector_type(8))) short;
using f32x4   = __attribute__((ext_vector_type(4))) float;

static __device__ __forceinline__ unsigned short f2bf(float f) {
    unsigned int u = __float_as_uint(f);
    u = (u + 0x7FFFu + ((u >> 16) & 1u)) >> 16;
    return (unsigned short)u;
}
static __device__ __forceinline__ float bf2f(unsigned short h) {
    return __uint_as_float(((unsigned int)h) << 16);
}
static __device__ __forceinline__ float dot8(bf16x8 a, bf16x8 b) {
    float s = 0.f;
    #pragma unroll
    for (int k = 0; k < 8; ++k)
        s = fmaf(bf2f((unsigned short)a[k]), bf2f((unsigned short)b[k]), s);
    return s;
}

// ---------------- one-shot: convert w1/w2 to bf16 ----------------
__global__ __launch_bounds__(256) void convert_w_kernel(
    const float* __restrict__ w1, const float* __restrict__ w2,
    unsigned short* __restrict__ w1b, unsigned short* __restrict__ w2b)
{
    int idx = blockIdx.x * 256 + threadIdx.x;
    const float* src = (idx < 8192) ? w1 : w2;
    unsigned short* dst = (idx < 8192) ? w1b : w2b;
    int off = ((idx < 8192) ? idx : idx - 8192) * 4;
    float4 v = *(const float4*)(src + off);
    ushort4 o;
    o.x = f2bf(v.x); o.y = f2bf(v.y); o.z = f2bf(v.z); o.w = f2bf(v.w);
    *(ushort4*)(dst + off) = o;
}

// ---------------- MFMA MLP (32 rows/block) + fused BN column partials ----------------
__global__ __launch_bounds__(256) void mlp_mfma_kernel(
    const float* __restrict__ x1, const float* __restrict__ x2,
    const unsigned short* __restrict__ w1b, const float* __restrict__ b1,
    const unsigned short* __restrict__ w2b, const float* __restrict__ b2,
    unsigned short* __restrict__ z1, unsigned short* __restrict__ z2,
    float* __restrict__ part_s, float* __restrict__ part_ss)
{
    __shared__ unsigned short hsh[32][264];
    const int t = threadIdx.x;
    const int w = t >> 6;
    const int lane = t & 63;
    const int g = lane >> 4;
    const int c16 = lane & 15;
    const int tensor = blockIdx.x >> 8;
    const int blk = blockIdx.x & 255;
    const int r0 = blk * 32;
    const float* __restrict__ x = tensor ? x2 : x1;
    unsigned short* __restrict__ z = tensor ? z2 : z1;

    // ---- layer 1 ----
    bf16x8 af[2][4];
    #pragma unroll
    for (int rf = 0; rf < 2; ++rf)
        #pragma unroll
        for (int ks = 0; ks < 4; ++ks) {
            const float* xp = x + (size_t)(r0 + rf * 16 + c16) * D + ks * 32 + g * 8;
            float4 u0 = *(const float4*)xp;
            float4 u1 = *(const float4*)(xp + 4);
            bf16x8 a;
            a[0] = f2bf(u0.x); a[1] = f2bf(u0.y); a[2] = f2bf(u0.z); a[3] = f2bf(u0.w);
            a[4] = f2bf(u1.x); a[5] = f2bf(u1.y); a[6] = f2bf(u1.z); a[7] = f2bf(u1.w);
            af[rf][ks] = a;
        }
    f32x4 acc1[2][4] = {};
    #pragma unroll
    for (int ks = 0; ks < 4; ++ks)
        #pragma unroll
        for (int nf = 0; nf < 4; ++nf) {
            int n = w * 64 + nf * 16 + c16;
            bf16x8 b = *(const bf16x8*)(w1b + (size_t)n * D + ks * 32 + g * 8);
            #pragma unroll
            for (int rf = 0; rf < 2; ++rf)
                acc1[rf][nf] = __builtin_amdgcn_mfma_f32_16x16x32_bf16(af[rf][ks], b, acc1[rf][nf], 0, 0, 0);
        }
    #pragma unroll
    for (int nf = 0; nf < 4; ++nf) {
        float bb = b1[w * 64 + nf * 16 + c16];
        #pragma unroll
        for (int rf = 0; rf < 2; ++rf)
            #pragma unroll
            for (int r = 0; r < 4; ++r)
                hsh[rf * 16 + g * 4 + r][w * 64 + nf * 16 + c16] = f2bf(fmaxf(acc1[rf][nf][r] + bb, 0.f));
    }
    __syncthreads();

    // ---- layer 2 ----
    f32x4 acc2[2][2] = {};
    #pragma unroll
    for (int ks = 0; ks < 8; ++ks) {
        bf16x8 a0 = *(const bf16x8*)(&hsh[c16][ks * 32 + g * 8]);
        bf16x8 a1 = *(const bf16x8*)(&hsh[16 + c16][ks * 32 + g * 8]);
        #pragma unroll
        for (int nf = 0; nf < 2; ++nf) {
            int n = w * 32 + nf * 16 + c16;
            bf16x8 b = *(const bf16x8*)(w2b + (size_t)n * 256 + ks * 32 + g * 8);
            acc2[0][nf] = __builtin_amdgcn_mfma_f32_16x16x32_bf16(a0, b, acc2[0][nf], 0, 0, 0);
            acc2[1][nf] = __builtin_amdgcn_mfma_f32_16x16x32_bf16(a1, b, acc2[1][nf], 0, 0, 0);
        }
    }

    // ---- store z + fused BN partials ----
    #pragma unroll
    for (int nf = 0; nf < 2; ++nf) {
        int col = w * 32 + nf * 16 + c16;
        float bb = b2[col];
        float s = 0.f, ss = 0.f;
        #pragma unroll
        for (int rf = 0; rf < 2; ++rf)
            #pragma unroll
            for (int r = 0; r < 4; ++r) {
                float v = acc2[rf][nf][r] + bb;
                z[(size_t)(r0 + rf * 16 + g * 4 + r) * D + col] = f2bf(v);
                s += v; ss += v * v;
            }
        s  += __shfl_xor(s, 16);  s  += __shfl_xor(s, 32);
        ss += __shfl_xor(ss, 16); ss += __shfl_xor(ss, 32);
        if (g == 0) {
            part_s [((size_t)tensor * 256 + blk) * D + col] = s;
            part_ss[((size_t)tensor * 256 + blk) * D + col] = ss;
        }
    }
}

// ---------------- BN reduce ----------------
__global__ __launch_bounds__(256) void bn_reduce_kernel(
    const float* __restrict__ part_s, const float* __restrict__ part_ss,
    const float* __restrict__ gamma,
    float* __restrict__ mu, float* __restrict__ sc)
{
    const int t = threadIdx.x;
    const int tensor = blockIdx.x >> 7;
    const int col = blockIdx.x & 127;
    float s  = part_s [((size_t)tensor * 256 + t) * D + col];
    float ss = part_ss[((size_t)tensor * 256 + t) * D + col];
    #pragma unroll
    for (int m = 32; m; m >>= 1) { s += __shfl_xor(s, m); ss += __shfl_xor(ss, m); }
    __shared__ float rs[4], rss[4];
    if ((t & 63) == 0) { rs[t >> 6] = s; rss[t >> 6] = ss; }
    __syncthreads();
    if (t == 0) {
        float S = rs[0] + rs[1] + rs[2] + rs[3];
        float SS = rss[0] + rss[1] + rss[2] + rss[3];
        float m = S / (float)N_TOT;
        float var = SS / (float)N_TOT - m * m;
        mu[tensor * D + col] = m;
        sc[tensor * D + col] = gamma[col] * rsqrtf(var + 1e-5f);
    }
}

// ---------------- BN apply + L2 normalize; z1 scaled by log2e ----------------
__global__ __launch_bounds__(256) void bn_l2_kernel(
    unsigned short* __restrict__ z1, unsigned short* __restrict__ z2,
    const float* __restrict__ mu, const float* __restrict__ sc,
    const float* __restrict__ beta)
{
    const int t = threadIdx.x;
    const int tensor = blockIdx.x >> 11;
    const int row = (blockIdx.x & 2047) * 4 + (t >> 6);
    const int lane = t & 63;
    unsigned short* __restrict__ yr = (tensor ? z2 : z1) + (size_t)row * D;
    const float* __restrict__ mub = mu + tensor * D;
    const float* __restrict__ scb = sc + tensor * D;

    ushort2 v = ((const ushort2*)yr)[lane];
    float2 m2 = ((const float2*)mub)[lane];
    float2 s2 = ((const float2*)scb)[lane];
    float2 b2 = ((const float2*)beta)[lane];
    float v0 = (bf2f(v.x) - m2.x) * s2.x + b2.x;
    float v1 = (bf2f(v.y) - m2.y) * s2.y + b2.y;
    float ssq = v0 * v0 + v1 * v1;
    #pragma unroll
    for (int m = 32; m; m >>= 1) ssq += __shfl_xor(ssq, m);
    float rn = rsqrtf(ssq);
    if (tensor == 0) rn *= LOG2E;   // pre-scale z1 so loss exp = exp2
    ushort2 o; o.x = f2bf(v0 * rn); o.y = f2bf(v1 * rn);
    ((ushort2*)yr)[lane] = o;
}

// ---------------- pos terms + diag/next exps (two-rows) ----------------
__global__ __launch_bounds__(256) void diag_kernel(
    const short* __restrict__ z1, const short* __restrict__ z2,
    float* __restrict__ posv, float* __restrict__ dden)
{
    const int t = threadIdx.x;
    const int row = blockIdx.x * 32 + (t >> 3);
    const int le = t & 7;
    const short* ap = z1 + (size_t)row * D + le * 16;
    const short* bp = z2 + (size_t)row * D + le * 16;
    const short* cp = z2 + (size_t)((row + 1) & (N_TOT - 1)) * D + le * 16;
    bf16x8 a0 = *(const bf16x8*)ap, a1 = *(const bf16x8*)(ap + 8);
    float s1 = dot8(a0, *(const bf16x8*)bp) + dot8(a1, *(const bf16x8*)(bp + 8));
    float s2 = dot8(a0, *(const bf16x8*)cp) + dot8(a1, *(const bf16x8*)(cp + 8));
    #pragma unroll
    for (int m = 1; m < 8; m <<= 1) { s1 += __shfl_xor(s1, m); s2 += __shfl_xor(s2, m); }
    if (le == 0) {
        bool two = (row & (SEQ_L - 1)) != (SEQ_L - 1);
        if (two) {
            posv[row] = (s1 + s2) * LN2;
            dden[row] = exp2f(s1) + exp2f(s2);
        } else {
            posv[row] = s1 * LN2;
        }
    }
}

// ---------------- collision corrections (vectorized int4 id-scan) ----------------
// 256 blocks x 256 threads: thread -> (row = bid*32 + t>>3, le = t&7); le scans
// j in [le*1024, le*1024+1024) via int4. two-rows: hits where seqj!=seqi and
// idj in {idi,idn}. non-two rows: hits where idj==idi and j!=i (ALL seqs).
// Rare hits recompute the dot and add exp2. Single writer per row.
__global__ __launch_bounds__(256) void corr_kernel(
    const short* __restrict__ z1, const short* __restrict__ z2,
    const int* __restrict__ ids, float* __restrict__ corr)
{
    const int t = threadIdx.x;
    const int row = blockIdx.x * 32 + (t >> 3);
    const int le = t & 7;

    const bool two = (row & (SEQ_L - 1)) != (SEQ_L - 1);
    const int idi  = ids[row];
    const int idn_s = two ? ids[(row + 1) & (N_TOT - 1)] : idi;
    const int seq_s = two ? (row >> 9) : -1;

    float cr = 0.f;
    const int4* idv = (const int4*)ids;
    #pragma unroll 4
    for (int k = 0; k < 256; ++k) {
        int jb = le * 256 + k;
        int4 v = idv[jb];
        int j0 = jb * 4;
        if ((j0 >> 9) != seq_s) {
            int hm = (((v.x == idi) | (v.x == idn_s)) & (j0 + 0 != row) ? 1 : 0)
                   | (((v.y == idi) | (v.y == idn_s)) & (j0 + 1 != row) ? 2 : 0)
                   | (((v.z == idi) | (v.z == idn_s)) & (j0 + 2 != row) ? 4 : 0)
                   | (((v.w == idi) | (v.w == idn_s)) & (j0 + 3 != row) ? 8 : 0);
            if (hm) {
                #pragma unroll
                for (int c = 0; c < 4; ++c)
                    if (hm & (1 << c)) {
                        int j = j0 + c;
                        float s = 0.f;
                        for (int k2 = 0; k2 < 16; ++k2) {
                            bf16x8 va = *(const bf16x8*)(z1 + (size_t)row * D + k2 * 8);
                            bf16x8 vb = *(const bf16x8*)(z2 + (size_t)j * D + k2 * 8);
                            s += dot8(va, vb);
                        }
                        cr += exp2f(s);
                    }
            }
        }
    }
    cr += __shfl_xor(cr, 1);
    cr += __shfl_xor(cr, 2);
    cr += __shfl_xor(cr, 4);
    if (le == 0) corr[row] = cr;
}

// ---------------- barrier-free streaming S + exp2 sum (full matrix, unmasked) ----------------
// grid 4096: chunk = bid&15 (-> XCD chunk%8: chunk z2 + z1 L2-hot),
// rb = (bid>>4)*32. Block = 32 z1-rows x 512 cols; wave w streams cols
// chunk*512 + w*128 in 8x 16-col steps. A-frags + den accumulators in
// registers; B-frags straight from L2. NO LDS / NO barriers in the loop ->
// compiler pipelines loads under MFMA+exp2; occupancy ~5 waves/SIMD.
__global__ __launch_bounds__(256) void loss_stream_kernel(
    const short* __restrict__ z1, const short* __restrict__ z2,
    float* __restrict__ den_part)
{
    const int t    = threadIdx.x;
    const int w    = t >> 6;
    const int lane = t & 63;
    const int g    = lane >> 4;
    const int c16  = lane & 15;

    const int chunk = blockIdx.x & (NCHUNK - 1);
    const int rb    = (blockIdx.x >> 4) * 32;
    const int jw    = chunk * CHUNK + w * 128;

    // A fragments: rows rb + rf*16 + c16, k = ks*32 + g*8 (verified pattern)
    bf16x8 af[2][4];
    #pragma unroll
    for (int rf = 0; rf < 2; ++rf)
        #pragma unroll
        for (int ks = 0; ks < 4; ++ks)
            af[rf][ks] = *(const bf16x8*)(z1 + (size_t)(rb + rf * 16 + c16) * D + ks * 32 + g * 8);

    float den[2][4] = {};

    #pragma unroll 1
    for (int it = 0; it < 8; ++it) {
        const int cb = jw + it * 16;
        bf16x8 bfr[4];
        #pragma unroll
        for (int ks = 0; ks < 4; ++ks)
            bfr[ks] = *(const bf16x8*)(z2 + (size_t)(cb + c16) * D + ks * 32 + g * 8);

        f32x4 acc0 = {}, acc1 = {};
        #pragma unroll
        for (int ks = 0; ks < 4; ++ks) {
            acc0 = __builtin_amdgcn_mfma_f32_16x16x32_bf16(af[0][ks], bfr[ks], acc0, 0, 0, 0);
            acc1 = __builtin_amdgcn_mfma_f32_16x16x32_bf16(af[1][ks], bfr[ks], acc1, 0, 0, 0);
        }
        #pragma unroll
        for (int r = 0; r < 4; ++r) {
            den[0][r] += exp2f(acc0[r]);
            den[1][r] += exp2f(acc1[r]);
        }
    }

    // 16-lane column reduce, then cross-wave combine (waves cover different cols)
    __shared__ float sh_den[4][32];
    #pragma unroll
    for (int rf = 0; rf < 2; ++rf)
        #pragma unroll
        for (int r = 0; r < 4; ++r) {
            float d = den[rf][r];
            d += __shfl_xor(d, 1);
            d += __shfl_xor(d, 2);
            d += __shfl_xor(d, 4);
            d += __shfl_xor(d, 8);
            if (c16 == 0) sh_den[w][rf * 16 + g * 4 + r] = d;
        }
    __syncthreads();
    if (t < 32)
        den_part[chunk * N_TOT + rb + t] =
            sh_den[0][t] + sh_den[1][t] + sh_den[2][t] + sh_den[3][t];
}

// ---------------- combine: den from partials + corrections; loss scalar ----------------
__global__ __launch_bounds__(1024) void loss_finish_kernel(
    const float* __restrict__ den_part, const float* __restrict__ posv,
    const float* __restrict__ dden, const float* __restrict__ corr,
    float* __restrict__ out)
{
    const int t = threadIdx.x;
    float v = 0.f;
    for (int k = 0; k < N_TOT / 1024; ++k) {
        int row = t + k * 1024;
        int seqb = row >> 9;
        float s_all = 0.f;
        #pragma unroll
        for (int q = 0; q < NCHUNK; ++q) s_all += den_part[q * N_TOT + row];
        bool two = ((row & (SEQ_L - 1)) != (SEQ_L - 1));
        float den = two ? (s_all - den_part[seqb * N_TOT + row] + dden[row] - corr[row])
                        : (s_all - corr[row]);
        float npos = two ? 2.f : 1.f;
        v += -(posv[row] - logf(den)) / npos;
    }
    #pragma unroll
    for (int m = 32; m; m >>= 1) v += __shfl_xor(v, m);
    __shared__ float red[16];
    if ((t & 63) == 0) red[t >> 6] = v;
    __syncthreads();
    if (t == 0) {
        float tot = 0.f;
        #pragma unroll
        for (int i = 0; i < 16; ++i) tot += red[i];
        out[0] = tot / (float)N_TOT;
    }
}

extern "C" void kernel_launch(void* const* d_in, const int* in_sizes, int n_in,
                              void* d_out, int out_size, void* d_ws, size_t ws_size,
                              hipStream_t stream)
{
    const int*   ids   = (const int*)d_in[0];
    const float* x1    = (const float*)d_in[2];
    const float* x2    = (const float*)d_in[3];
    const float* w1    = (const float*)d_in[4];
    const float* b1    = (const float*)d_in[5];
    const float* w2    = (const float*)d_in[6];
    const float* b2    = (const float*)d_in[7];
    const float* gamma = (const float*)d_in[8];
    const float* beta  = (const float*)d_in[9];

    char* ws = (char*)d_ws;
    unsigned short* z1b = (unsigned short*)ws;                          // 2MB
    unsigned short* z2b = (unsigned short*)(ws + (2u << 20));           // 2MB
    float* part_s  = (float*)(ws + (4u << 20));                         // 256KB
    float* part_ss = part_s + 2 * 256 * D;                              // 256KB
    float* mu      = part_ss + 2 * 256 * D;
    float* sc      = mu + 2 * D;
    float* den_part = sc + 2 * D;                                       // 512KB
    float* posv    = den_part + NCHUNK * N_TOT;                         // 32KB
    float* dden    = posv + N_TOT;                                      // 32KB
    float* corr    = dden + N_TOT;                                      // 32KB
    unsigned short* w1b = (unsigned short*)(corr + N_TOT);              // 64KB
    unsigned short* w2b = w1b + 256 * D;                                // 64KB

    convert_w_kernel<<<64, 256, 0, stream>>>(w1, w2, w1b, w2b);
    mlp_mfma_kernel<<<512, 256, 0, stream>>>(x1, x2, w1b, b1, w2b, b2,
                                             z1b, z2b, part_s, part_ss);
    bn_reduce_kernel<<<256, 256, 0, stream>>>(part_s, part_ss, gamma, mu, sc);
    bn_l2_kernel<<<4096, 256, 0, stream>>>(z1b, z2b, mu, sc, beta);
    diag_kernel<<<256, 256, 0, stream>>>((const short*)z1b, (const short*)z2b,
                                         posv, dden);
    corr_kernel<<<256, 256, 0, stream>>>((const short*)z1b, (const short*)z2b,
                                         ids, corr);
    loss_stream_kernel<<<4096, 256, 0, stream>>>((const short*)z1b, (const short*)z2b,
                                                 den_part);
    loss_finish_kernel<<<1, 1024, 0, stream>>>(den_part, posv, dden, corr,
                                               (float*)d_out);
}

// Round 12
// 87.023 us; speedup vs baseline: 2.1225x; 2.1225x over previous
//
#include <hip/hip_runtime.h>

#define N_TOT 8192
#define SEQ_L 512
#define D 128
#define NCHUNK 16
#define CHUNK (N_TOT / NCHUNK)   // 512 cols per j-chunk == one seq block
#define NJT (CHUNK / 64)         // 8 64-col tiles per chunk
#define LOG2E 1.4426950408889634f
#define LN2   0.6931471805599453f

using bf16x8  = __attribute__((ext_vector_type(8))) short;
using f32x4   = __attribute__((ext_vector_type(4))) float;

static __device__ __forceinline__ unsigned short f2bf(float f) {
    unsigned int u = __float_as_uint(f);
    u = (u + 0x7FFFu + ((u >> 16) & 1u)) >> 16;
    return (unsigned short)u;
}
static __device__ __forceinline__ float bf2f(unsigned short h) {
    return __uint_as_float(((unsigned int)h) << 16);
}
static __device__ __forceinline__ float dot8(bf16x8 a, bf16x8 b) {
    float s = 0.f;
    #pragma unroll
    for (int k = 0; k < 8; ++k)
        s = fmaf(bf2f((unsigned short)a[k]), bf2f((unsigned short)b[k]), s);
    return s;
}

// ---------------- one-shot: convert w1/w2 to bf16 ----------------
__global__ __launch_bounds__(256) void convert_w_kernel(
    const float* __restrict__ w1, const float* __restrict__ w2,
    unsigned short* __restrict__ w1b, unsigned short* __restrict__ w2b)
{
    int idx = blockIdx.x * 256 + threadIdx.x;
    const float* src = (idx < 8192) ? w1 : w2;
    unsigned short* dst = (idx < 8192) ? w1b : w2b;
    int off = ((idx < 8192) ? idx : idx - 8192) * 4;
    float4 v = *(const float4*)(src + off);
    ushort4 o;
    o.x = f2bf(v.x); o.y = f2bf(v.y); o.z = f2bf(v.z); o.w = f2bf(v.w);
    *(ushort4*)(dst + off) = o;
}

// ---------------- MFMA MLP (32 rows/block) + fused BN column partials ----------------
__global__ __launch_bounds__(256) void mlp_mfma_kernel(
    const float* __restrict__ x1, const float* __restrict__ x2,
    const unsigned short* __restrict__ w1b, const float* __restrict__ b1,
    const unsigned short* __restrict__ w2b, const float* __restrict__ b2,
    unsigned short* __restrict__ z1, unsigned short* __restrict__ z2,
    float* __restrict__ part_s, float* __restrict__ part_ss)
{
    __shared__ unsigned short hsh[32][264];
    const int t = threadIdx.x;
    const int w = t >> 6;
    const int lane = t & 63;
    const int g = lane >> 4;
    const int c16 = lane & 15;
    const int tensor = blockIdx.x >> 8;
    const int blk = blockIdx.x & 255;
    const int r0 = blk * 32;
    const float* __restrict__ x = tensor ? x2 : x1;
    unsigned short* __restrict__ z = tensor ? z2 : z1;

    // ---- layer 1 ----
    bf16x8 af[2][4];
    #pragma unroll
    for (int rf = 0; rf < 2; ++rf)
        #pragma unroll
        for (int ks = 0; ks < 4; ++ks) {
            const float* xp = x + (size_t)(r0 + rf * 16 + c16) * D + ks * 32 + g * 8;
            float4 u0 = *(const float4*)xp;
            float4 u1 = *(const float4*)(xp + 4);
            bf16x8 a;
            a[0] = f2bf(u0.x); a[1] = f2bf(u0.y); a[2] = f2bf(u0.z); a[3] = f2bf(u0.w);
            a[4] = f2bf(u1.x); a[5] = f2bf(u1.y); a[6] = f2bf(u1.z); a[7] = f2bf(u1.w);
            af[rf][ks] = a;
        }
    f32x4 acc1[2][4] = {};
    #pragma unroll
    for (int ks = 0; ks < 4; ++ks)
        #pragma unroll
        for (int nf = 0; nf < 4; ++nf) {
            int n = w * 64 + nf * 16 + c16;
            bf16x8 b = *(const bf16x8*)(w1b + (size_t)n * D + ks * 32 + g * 8);
            #pragma unroll
            for (int rf = 0; rf < 2; ++rf)
                acc1[rf][nf] = __builtin_amdgcn_mfma_f32_16x16x32_bf16(af[rf][ks], b, acc1[rf][nf], 0, 0, 0);
        }
    #pragma unroll
    for (int nf = 0; nf < 4; ++nf) {
        float bb = b1[w * 64 + nf * 16 + c16];
        #pragma unroll
        for (int rf = 0; rf < 2; ++rf)
            #pragma unroll
            for (int r = 0; r < 4; ++r)
                hsh[rf * 16 + g * 4 + r][w * 64 + nf * 16 + c16] = f2bf(fmaxf(acc1[rf][nf][r] + bb, 0.f));
    }
    __syncthreads();

    // ---- layer 2 ----
    f32x4 acc2[2][2] = {};
    #pragma unroll
    for (int ks = 0; ks < 8; ++ks) {
        bf16x8 a0 = *(const bf16x8*)(&hsh[c16][ks * 32 + g * 8]);
        bf16x8 a1 = *(const bf16x8*)(&hsh[16 + c16][ks * 32 + g * 8]);
        #pragma unroll
        for (int nf = 0; nf < 2; ++nf) {
            int n = w * 32 + nf * 16 + c16;
            bf16x8 b = *(const bf16x8*)(w2b + (size_t)n * 256 + ks * 32 + g * 8);
            acc2[0][nf] = __builtin_amdgcn_mfma_f32_16x16x32_bf16(a0, b, acc2[0][nf], 0, 0, 0);
            acc2[1][nf] = __builtin_amdgcn_mfma_f32_16x16x32_bf16(a1, b, acc2[1][nf], 0, 0, 0);
        }
    }

    // ---- store z + fused BN partials ----
    #pragma unroll
    for (int nf = 0; nf < 2; ++nf) {
        int col = w * 32 + nf * 16 + c16;
        float bb = b2[col];
        float s = 0.f, ss = 0.f;
        #pragma unroll
        for (int rf = 0; rf < 2; ++rf)
            #pragma unroll
            for (int r = 0; r < 4; ++r) {
                float v = acc2[rf][nf][r] + bb;
                z[(size_t)(r0 + rf * 16 + g * 4 + r) * D + col] = f2bf(v);
                s += v; ss += v * v;
            }
        s  += __shfl_xor(s, 16);  s  += __shfl_xor(s, 32);
        ss += __shfl_xor(ss, 16); ss += __shfl_xor(ss, 32);
        if (g == 0) {
            part_s [((size_t)tensor * 256 + blk) * D + col] = s;
            part_ss[((size_t)tensor * 256 + blk) * D + col] = ss;
        }
    }
}

// ---------------- BN reduce ----------------
__global__ __launch_bounds__(256) void bn_reduce_kernel(
    const float* __restrict__ part_s, const float* __restrict__ part_ss,
    const float* __restrict__ gamma,
    float* __restrict__ mu, float* __restrict__ sc)
{
    const int t = threadIdx.x;
    const int tensor = blockIdx.x >> 7;
    const int col = blockIdx.x & 127;
    float s  = part_s [((size_t)tensor * 256 + t) * D + col];
    float ss = part_ss[((size_t)tensor * 256 + t) * D + col];
    #pragma unroll
    for (int m = 32; m; m >>= 1) { s += __shfl_xor(s, m); ss += __shfl_xor(ss, m); }
    __shared__ float rs[4], rss[4];
    if ((t & 63) == 0) { rs[t >> 6] = s; rss[t >> 6] = ss; }
    __syncthreads();
    if (t == 0) {
        float S = rs[0] + rs[1] + rs[2] + rs[3];
        float SS = rss[0] + rss[1] + rss[2] + rss[3];
        float m = S / (float)N_TOT;
        float var = SS / (float)N_TOT - m * m;
        mu[tensor * D + col] = m;
        sc[tensor * D + col] = gamma[col] * rsqrtf(var + 1e-5f);
    }
}

// ---------------- BN apply + L2 normalize; z1 scaled by log2e ----------------
__global__ __launch_bounds__(256) void bn_l2_kernel(
    unsigned short* __restrict__ z1, unsigned short* __restrict__ z2,
    const float* __restrict__ mu, const float* __restrict__ sc,
    const float* __restrict__ beta)
{
    const int t = threadIdx.x;
    const int tensor = blockIdx.x >> 11;
    const int row = (blockIdx.x & 2047) * 4 + (t >> 6);
    const int lane = t & 63;
    unsigned short* __restrict__ yr = (tensor ? z2 : z1) + (size_t)row * D;
    const float* __restrict__ mub = mu + tensor * D;
    const float* __restrict__ scb = sc + tensor * D;

    ushort2 v = ((const ushort2*)yr)[lane];
    float2 m2 = ((const float2*)mub)[lane];
    float2 s2 = ((const float2*)scb)[lane];
    float2 b2 = ((const float2*)beta)[lane];
    float v0 = (bf2f(v.x) - m2.x) * s2.x + b2.x;
    float v1 = (bf2f(v.y) - m2.y) * s2.y + b2.y;
    float ssq = v0 * v0 + v1 * v1;
    #pragma unroll
    for (int m = 32; m; m >>= 1) ssq += __shfl_xor(ssq, m);
    float rn = rsqrtf(ssq);
    if (tensor == 0) rn *= LOG2E;   // pre-scale z1 so loss exp = exp2
    ushort2 o; o.x = f2bf(v0 * rn); o.y = f2bf(v1 * rn);
    ((ushort2*)yr)[lane] = o;
}

// ---------------- diagonal-chunk work: pos terms + diag-chunk denominators ----------------
__global__ __launch_bounds__(256) void diag_kernel(
    const short* __restrict__ z1, const short* __restrict__ z2,
    const int* __restrict__ ids,
    float* __restrict__ posv, float* __restrict__ dden)
{
    const int t = threadIdx.x;
    if (blockIdx.x < 256) {
        const int row = blockIdx.x * 32 + (t >> 3);
        const int le = t & 7;
        const short* ap = z1 + (size_t)row * D + le * 16;
        const short* bp = z2 + (size_t)row * D + le * 16;
        const short* cp = z2 + (size_t)((row + 1) & (N_TOT - 1)) * D + le * 16;
        bf16x8 a0 = *(const bf16x8*)ap, a1 = *(const bf16x8*)(ap + 8);
        float s1 = dot8(a0, *(const bf16x8*)bp) + dot8(a1, *(const bf16x8*)(bp + 8));
        float s2 = dot8(a0, *(const bf16x8*)cp) + dot8(a1, *(const bf16x8*)(cp + 8));
        #pragma unroll
        for (int m = 1; m < 8; m <<= 1) { s1 += __shfl_xor(s1, m); s2 += __shfl_xor(s2, m); }
        if (le == 0) {
            bool two = (row & (SEQ_L - 1)) != (SEQ_L - 1);
            if (two) {
                posv[row] = (s1 + s2) * LN2;
                dden[row] = exp2f(s1) + exp2f(s2);
            } else {
                posv[row] = s1 * LN2;
            }
        }
    } else {
        const int sr = blockIdx.x - 256;
        const int i = sr * SEQ_L + (SEQ_L - 1);
        const int jbase = sr * SEQ_L;
        const int idi_ = ids[i];
        float acc = 0.f;
        #pragma unroll
        for (int c = 0; c < 2; ++c) {
            int j = jbase + t * 2 + c;
            float s = 0.f;
            for (int k = 0; k < 16; ++k) {
                bf16x8 va = *(const bf16x8*)(z1 + (size_t)i * D + k * 8);
                bf16x8 vb = *(const bf16x8*)(z2 + (size_t)j * D + k * 8);
                s += dot8(va, vb);
            }
            bool m = (ids[j] != idi_) | (j == i);
            acc += m ? exp2f(s) : 0.f;
        }
        #pragma unroll
        for (int m = 32; m; m >>= 1) acc += __shfl_xor(acc, m);
        __shared__ float red[4];
        if ((t & 63) == 0) red[t >> 6] = acc;
        __syncthreads();
        if (t == 0) dden[i] = red[0] + red[1] + red[2] + red[3];
    }
}

// ---------------- MFMA S-tile + masked exp2 denominators, OFF-DIAGONAL chunks ----------------
// grid 480 = 15 chunks x 32 row-blocks. Block = 256 rows x 512 cols; wave w
// owns 64 rows (rf=0..3) -> each ds_read_b128 feeds 4 MFMAs; total LDS read
// volume halved vs the 32-row/wave R9 version (the identified bottleneck).
// Off-diagonal => mask is just (idj!=idi)&(idj!=idn_s); no eq/pos paths.
// 2-phase dbuf, reg-staged (T14): issue stage loads early, ds_write after
// MFMA, one barrier per jt, epilogue post-barrier.
__global__ __launch_bounds__(256, 2) void loss_mfma_kernel(
    const short* __restrict__ z1, const short* __restrict__ z2,
    const int* __restrict__ ids,
    float* __restrict__ den_part)
{
    const int t    = threadIdx.x;
    const int w    = t >> 6;
    const int lane = t & 63;
    const int g    = lane >> 4;
    const int c16  = lane & 15;

    const int c15 = blockIdx.x % 15;
    const int rbi = blockIdx.x / 15;          // 0..31
    const int rb  = rbi * 256;
    const int seqb = rb >> 9;
    const int chunk = c15 + (c15 >= seqb);    // skip diagonal chunk
    const int jbase = chunk * CHUNK;

    const int i_wb = rb + w * 64;

    __shared__ __align__(16) unsigned char z2s[2][64 * 256];  // 2 x 16KB

    const int srow = t >> 2;
    const int sq   = t & 3;
    const int wxor = (srow & 7) << 4;
    const int rxor = (c16 & 7) << 4;

    // A fragments: 4 row-frags x 4 k-steps (verified pattern)
    bf16x8 af[4][4];
    #pragma unroll
    for (int rf = 0; rf < 4; ++rf)
        #pragma unroll
        for (int ks = 0; ks < 4; ++ks)
            af[rf][ks] = *(const bf16x8*)(z1 + (size_t)(i_wb + rf * 16 + c16) * D + ks * 32 + g * 8);

    // row metadata: idi + sentinel-folded idn
    int idi[4][4], idn_s[4][4];
    #pragma unroll
    for (int rf = 0; rf < 4; ++rf)
        #pragma unroll
        for (int r = 0; r < 4; ++r) {
            int i = i_wb + rf * 16 + g * 4 + r;
            idi[rf][r] = ids[i];
            bool tw = ((i & (SEQ_L - 1)) != (SEQ_L - 1));
            idn_s[rf][r] = tw ? ids[(i + 1) & (N_TOT - 1)] : idi[rf][r];
        }

    // prologue: stage tile 0
    #pragma unroll
    for (int it = 0; it < 4; ++it) {
        bf16x8 v = *(const bf16x8*)(z2 + (size_t)(jbase + srow) * D + sq * 8 + it * 32);
        *(bf16x8*)&z2s[0][srow * 256 + ((sq * 16 + it * 64) ^ wxor)] = v;
    }
    __syncthreads();

    float den[4][4] = {};
    int cbuf = 0;

    #pragma unroll 1
    for (int jt = 0; jt < NJT; ++jt) {
        const int cb = jbase + jt * 64;

        // stage next tile into regs (T14 issue-early)
        bf16x8 stg[4];
        if (jt + 1 < NJT) {
            #pragma unroll
            for (int it = 0; it < 4; ++it)
                stg[it] = *(const bf16x8*)(z2 + (size_t)(cb + 64 + srow) * D + sq * 8 + it * 32);
        }

        int idj[4];
        #pragma unroll
        for (int nf = 0; nf < 4; ++nf) idj[nf] = ids[cb + nf * 16 + c16];

        // MFMA: one ds_read_b128 feeds 4 MFMAs (rf)
        f32x4 acc[4][4] = {};
        #pragma unroll
        for (int ks = 0; ks < 4; ++ks)
            #pragma unroll
            for (int nf = 0; nf < 4; ++nf) {
                bf16x8 b = *(const bf16x8*)&z2s[cbuf][(nf * 16 + c16) * 256 + ((ks * 64 + g * 16) ^ rxor)];
                #pragma unroll
                for (int rf = 0; rf < 4; ++rf)
                    acc[rf][nf] = __builtin_amdgcn_mfma_f32_16x16x32_bf16(af[rf][ks], b, acc[rf][nf], 0, 0, 0);
            }

        // write next buffer, then one barrier per jt
        if (jt + 1 < NJT) {
            #pragma unroll
            for (int it = 0; it < 4; ++it)
                *(bf16x8*)&z2s[cbuf ^ 1][srow * 256 + ((sq * 16 + it * 64) ^ wxor)] = stg[it];
        }
        __syncthreads();

        // post-barrier epilogue: masked exp2 accumulate
        #pragma unroll
        for (int rf = 0; rf < 4; ++rf)
            #pragma unroll
            for (int nf = 0; nf < 4; ++nf)
                #pragma unroll
                for (int r = 0; r < 4; ++r) {
                    float e = exp2f(acc[rf][nf][r]);
                    bool m = (idj[nf] != idi[rf][r]) & (idj[nf] != idn_s[rf][r]);
                    den[rf][r] += m ? e : 0.f;
                }
        cbuf ^= 1;
    }

    // 16-lane column reduce; single writer per (chunk,row)
    #pragma unroll
    for (int rf = 0; rf < 4; ++rf)
        #pragma unroll
        for (int r = 0; r < 4; ++r) {
            float dsum = den[rf][r];
            dsum += __shfl_xor(dsum, 1);
            dsum += __shfl_xor(dsum, 2);
            dsum += __shfl_xor(dsum, 4);
            dsum += __shfl_xor(dsum, 8);
            if (c16 == 0)
                den_part[chunk * N_TOT + i_wb + rf * 16 + g * 4 + r] = dsum;
        }
}

// ---------------- combine: den = dden + off-diag chunks; loss scalar ----------------
__global__ __launch_bounds__(1024) void loss_finish_kernel(
    const float* __restrict__ den_part, const float* __restrict__ posv,
    const float* __restrict__ dden, float* __restrict__ out)
{
    const int t = threadIdx.x;
    float v = 0.f;
    for (int k = 0; k < N_TOT / 1024; ++k) {
        int row = t + k * 1024;
        int seqb = row >> 9;
        float den = dden[row];
        #pragma unroll
        for (int q = 0; q < NCHUNK; ++q)
            if (q != seqb) den += den_part[q * N_TOT + row];
        bool two = ((row & (SEQ_L - 1)) != (SEQ_L - 1));
        float npos = two ? 2.f : 1.f;
        v += -(posv[row] - logf(den)) / npos;
    }
    #pragma unroll
    for (int m = 32; m; m >>= 1) v += __shfl_xor(v, m);
    __shared__ float red[16];
    if ((t & 63) == 0) red[t >> 6] = v;
    __syncthreads();
    if (t == 0) {
        float tot = 0.f;
        #pragma unroll
        for (int i = 0; i < 16; ++i) tot += red[i];
        out[0] = tot / (float)N_TOT;
    }
}

extern "C" void kernel_launch(void* const* d_in, const int* in_sizes, int n_in,
                              void* d_out, int out_size, void* d_ws, size_t ws_size,
                              hipStream_t stream)
{
    const int*   ids   = (const int*)d_in[0];
    const float* x1    = (const float*)d_in[2];
    const float* x2    = (const float*)d_in[3];
    const float* w1    = (const float*)d_in[4];
    const float* b1    = (const float*)d_in[5];
    const float* w2    = (const float*)d_in[6];
    const float* b2    = (const float*)d_in[7];
    const float* gamma = (const float*)d_in[8];
    const float* beta  = (const float*)d_in[9];

    char* ws = (char*)d_ws;
    unsigned short* z1b = (unsigned short*)ws;                          // 2MB
    unsigned short* z2b = (unsigned short*)(ws + (2u << 20));           // 2MB
    float* part_s  = (float*)(ws + (4u << 20));                         // 256KB
    float* part_ss = part_s + 2 * 256 * D;                              // 256KB
    float* mu      = part_ss + 2 * 256 * D;
    float* sc      = mu + 2 * D;
    float* den_part = sc + 2 * D;                                       // 512KB
    float* posv    = den_part + NCHUNK * N_TOT;                         // 32KB
    float* dden    = posv + N_TOT;                                      // 32KB
    unsigned short* w1b = (unsigned short*)(dden + N_TOT);              // 64KB
    unsigned short* w2b = w1b + 256 * D;                                // 64KB

    convert_w_kernel<<<64, 256, 0, stream>>>(w1, w2, w1b, w2b);
    mlp_mfma_kernel<<<512, 256, 0, stream>>>(x1, x2, w1b, b1, w2b, b2,
                                             z1b, z2b, part_s, part_ss);
    bn_reduce_kernel<<<256, 256, 0, stream>>>(part_s, part_ss, gamma, mu, sc);
    bn_l2_kernel<<<4096, 256, 0, stream>>>(z1b, z2b, mu, sc, beta);
    diag_kernel<<<272, 256, 0, stream>>>((const short*)z1b, (const short*)z2b,
                                         ids, posv, dden);
    loss_mfma_kernel<<<480, 256, 0, stream>>>((const short*)z1b, (const short*)z2b,
                                              ids, den_part);
    loss_finish_kernel<<<1, 1024, 0, stream>>>(den_part, posv, dden, (float*)d_out);
}